// Round 9
// baseline (638.449 us; speedup 1.0000x reference)
//
#include <hip/hip_runtime.h>

#define HID 50
#define LAT 16
#define NW  4          // waves per block (fully independent, no LDS, no barriers)
#define BLK (NW * 64)
#define MPW 16         // batch elements per wave
#define LOG2E2 2.8853900817779268f   // 2*log2(e), folded into ODE layer-1 weights

typedef __attribute__((ext_vector_type(8))) short short8;   // 8 bf16 = 4 VGPRs
typedef __attribute__((ext_vector_type(4))) float f32x4;
typedef __attribute__((ext_vector_type(4))) unsigned uint4v;

#define MFMA16(a, b, c) __builtin_amdgcn_mfma_f32_16x16x32_bf16(a, b, c, 0, 0, 0)

// pack two fp32 -> dword of 2 bf16 (round-half-up): low=lo, high=hi
// (R7-proven v_perm path; R8's v_cvt_pk_bf16_f32 asm was a NaN suspect)
__device__ __forceinline__ unsigned pkbf(float lo, float hi) {
    unsigned ul = __builtin_bit_cast(unsigned, lo) + 0x8000u;
    unsigned uh = __builtin_bit_cast(unsigned, hi) + 0x8000u;
    return __builtin_amdgcn_perm(uh, ul, 0x07060302u);  // [uh.hi16 | ul.hi16]
}

// tanh(x) given s = 2*log2(e)*x (pre-scaled via MFMA weights).
// tanh = 1 - 2/(1+2^s); reciprocal via magic-init + 2 Newton (rel err ~6e-6).
// exp2 via builtin (compiler-known trans op -> hazards handled, unlike raw asm).
// Reachable range: |s| <~ 40 (dynamics) and s=80 (sat slot): y in [1, 2^81),
// magic init stays positive-normal, Newton converges; y=1 -> tanh=-1 exact.
__device__ __forceinline__ float tanh_s(float s) {
    float e = __builtin_amdgcn_exp2f(s);
    float y = e + 1.0f;
    float r = __builtin_bit_cast(float, 0x7EF311C3u - __builtin_bit_cast(unsigned, y));
    r = r * __builtin_fmaf(-y, r, 2.0f);
    r = r * __builtin_fmaf(-y, r, 2.0f);
    return __builtin_fmaf(-2.0f, r, 1.0f);
}

// ---- A-frag builders (weights as MFMA A-operand; one-time setup) ----
// Layer-1 (W[Kreal x 50] row-major, transposed use): A-row m holds hid unit
// kappa(ti,m) = 32*(ti>>1) + 8*(m>>2) + 4*(ti&1) + (m&3); this permutation makes
// GEMM1's CD output registers coincide with GEMM2's B-frag slots (no shuffle).
// k-slot (q,j): j<4 -> input row 4q+j; (q==0,j==4) -> bias*scale; kappa==63 ->
// satval at the bias slot (satval already in the activation's input domain).
__device__ __forceinline__ short8 afrag1(const float* __restrict__ W, const float* __restrict__ bias,
                                         int Kreal, int ti, int q, int m,
                                         float scale, float satval) {
    int kap = 32 * (ti >> 1) + 8 * (m >> 2) + 4 * (ti & 1) + (m & 3);
    float e[8];
#pragma unroll
    for (int j = 0; j < 8; j++) {
        float f = 0.0f;
        if (kap < HID) {
            if (j < 4) {
                int row = 4 * q + j;
                if (row < Kreal) f = W[row * HID + kap] * scale;
            } else if (j == 4 && q == 0) f = bias[kap] * scale;
        } else if (kap == 63) {
            if (j == 4 && q == 0) f = satval;
        }
        e[j] = f;
    }
    uint4v d;
#pragma unroll
    for (int p = 0; p < 4; p++) d[p] = pkbf(e[2 * p], e[2 * p + 1]);
    return __builtin_bit_cast(short8, d);
}

// Layer-2 (W2[50 x N2] row-major): A2[m][kap] = W2[kap][m] for kap<50, bias at kap==63.
__device__ __forceinline__ short8 afrag2(const float* __restrict__ W2, const float* __restrict__ b2,
                                         int N2, int chunk, int q, int m) {
    float e[8];
#pragma unroll
    for (int j = 0; j < 8; j++) {
        int kap = 32 * chunk + 8 * q + j;
        float f = 0.0f;
        if (m < N2) {
            if (kap < HID)      f = W2[kap * N2 + m];
            else if (kap == 63) f = b2[m];
        }
        e[j] = f;
    }
    uint4v d;
#pragma unroll
    for (int p = 0; p < 4; p++) d[p] = pkbf(e[2 * p], e[2 * p + 1]);
    return __builtin_bit_cast(short8, d);
}

__global__ void __launch_bounds__(BLK, 4)
node_kernel(const float* __restrict__ x0, const float* __restrict__ tt,
            const float* __restrict__ We1, const float* __restrict__ be1,
            const float* __restrict__ We2, const float* __restrict__ be2,
            const float* __restrict__ Wo1, const float* __restrict__ bo1,
            const float* __restrict__ Wo2, const float* __restrict__ bo2,
            const float* __restrict__ Wd1, const float* __restrict__ bd1,
            const float* __restrict__ Wd2, const float* __restrict__ bd2,
            float* __restrict__ out, int B, int T) {
    const int lane = threadIdx.x & 63;
    const int q    = lane >> 4;          // quad
    const int c    = lane & 15;          // batch col in B/CD frags; row m in A frags
    const int wid  = threadIdx.x >> 6;
    const int wbase = blockIdx.x * (NW * MPW) + wid * MPW;

    const f32x4 zero4 = {0.0f, 0.0f, 0.0f, 0.0f};
    const unsigned biasdw = (q == 0) ? 0x3F80u : 0u;   // bf16(1.0) at k-slot j=4

    // ---- Encoder (transient frags): z^T = We2^T @ relu(We1^T @ x^T) ----
    f32x4 z;
    {
        uint4v bx = {0u, 0u, 0u, 0u};
        if (q == 0) {  // x at k=0,1; bias 1.0 at k=4
            bx[0] = pkbf(x0[2 * (wbase + c)], x0[2 * (wbase + c) + 1]);
            bx[2] = 0x3F80u;
        }
        short8 Bx = __builtin_bit_cast(short8, bx);
        f32x4 h0 = MFMA16(afrag1(We1, be1, 2, 0, q, c, 1.0f, 1.0f), Bx, zero4);
        f32x4 h1 = MFMA16(afrag1(We1, be1, 2, 1, q, c, 1.0f, 1.0f), Bx, zero4);
        f32x4 h2 = MFMA16(afrag1(We1, be1, 2, 2, q, c, 1.0f, 1.0f), Bx, zero4);
        f32x4 h3 = MFMA16(afrag1(We1, be1, 2, 3, q, c, 1.0f, 1.0f), Bx, zero4);
        uint4v d0 = {pkbf(fmaxf(h0[0], 0.f), fmaxf(h0[1], 0.f)), pkbf(fmaxf(h0[2], 0.f), fmaxf(h0[3], 0.f)),
                     pkbf(fmaxf(h1[0], 0.f), fmaxf(h1[1], 0.f)), pkbf(fmaxf(h1[2], 0.f), fmaxf(h1[3], 0.f))};
        uint4v d1 = {pkbf(fmaxf(h2[0], 0.f), fmaxf(h2[1], 0.f)), pkbf(fmaxf(h2[2], 0.f), fmaxf(h2[3], 0.f)),
                     pkbf(fmaxf(h3[0], 0.f), fmaxf(h3[1], 0.f)), pkbf(fmaxf(h3[2], 0.f), fmaxf(h3[3], 0.f))};
        z = MFMA16(afrag2(We2, be2, 16, 1, q, c), __builtin_bit_cast(short8, d1),
            MFMA16(afrag2(We2, be2, 16, 0, q, c), __builtin_bit_cast(short8, d0), zero4));
    }

    // ---- persistent weight A-frags (VGPRs for whole kernel) ----
    // ODE layer-1 pre-scaled by 2*log2(e): MFMA emits the exp2 argument directly.
    short8 A1o[4], A1d[4], A2o[2], A2d[2];
#pragma unroll
    for (int ti = 0; ti < 4; ti++) {
        A1o[ti] = afrag1(Wo1, bo1, LAT, ti, q, c, LOG2E2, 80.0f);  // tanh_s(80)==1.0
        A1d[ti] = afrag1(Wd1, bd1, LAT, ti, q, c, 1.0f, 1.0f);     // relu(1)==1.0
    }
#pragma unroll
    for (int ch = 0; ch < 2; ch++) {
        A2o[ch] = afrag2(Wo2, bo2, LAT, ch, q, c);
        A2d[ch] = afrag2(Wd2, bd2, 1, ch, q, c);
    }

    // z (CD layout: lat 4q+r, batch c) -> GEMM1 B-frag: k(j<4)=lat 4q+j, bias at k=4
    auto mkzfrag = [&](f32x4 zz) -> short8 {
        uint4v d = {pkbf(zz[0], zz[1]), pkbf(zz[2], zz[3]), biasdw, 0u};
        return __builtin_bit_cast(short8, d);
    };

    // ODE func, all in registers: 6 MFMA + 16 tanh_s + 8 packs
    auto odef = [&](short8 zf) -> f32x4 {
        f32x4 h0 = MFMA16(A1o[0], zf, zero4);
        f32x4 h1 = MFMA16(A1o[1], zf, zero4);
        f32x4 h2 = MFMA16(A1o[2], zf, zero4);
        f32x4 h3 = MFMA16(A1o[3], zf, zero4);
        uint4v d0 = {pkbf(tanh_s(h0[0]), tanh_s(h0[1])), pkbf(tanh_s(h0[2]), tanh_s(h0[3])),
                     pkbf(tanh_s(h1[0]), tanh_s(h1[1])), pkbf(tanh_s(h1[2]), tanh_s(h1[3]))};
        uint4v d1 = {pkbf(tanh_s(h2[0]), tanh_s(h2[1])), pkbf(tanh_s(h2[2]), tanh_s(h2[3])),
                     pkbf(tanh_s(h3[0]), tanh_s(h3[1])), pkbf(tanh_s(h3[2]), tanh_s(h3[3]))};
        return MFMA16(A2o[1], __builtin_bit_cast(short8, d1),
               MFMA16(A2o[0], __builtin_bit_cast(short8, d0), zero4));
    };

    // decoder: y[c] lands in reg0 of q==0 lanes
    auto decode = [&](short8 zf) -> f32x4 {
        f32x4 h0 = MFMA16(A1d[0], zf, zero4);
        f32x4 h1 = MFMA16(A1d[1], zf, zero4);
        f32x4 h2 = MFMA16(A1d[2], zf, zero4);
        f32x4 h3 = MFMA16(A1d[3], zf, zero4);
        uint4v d0 = {pkbf(fmaxf(h0[0], 0.f), fmaxf(h0[1], 0.f)), pkbf(fmaxf(h0[2], 0.f), fmaxf(h0[3], 0.f)),
                     pkbf(fmaxf(h1[0], 0.f), fmaxf(h1[1], 0.f)), pkbf(fmaxf(h1[2], 0.f), fmaxf(h1[3], 0.f))};
        uint4v d1 = {pkbf(fmaxf(h2[0], 0.f), fmaxf(h2[1], 0.f)), pkbf(fmaxf(h2[2], 0.f), fmaxf(h2[3], 0.f)),
                     pkbf(fmaxf(h3[0], 0.f), fmaxf(h3[1], 0.f)), pkbf(fmaxf(h3[2], 0.f), fmaxf(h3[3], 0.f))};
        return MFMA16(A2d[1], __builtin_bit_cast(short8, d1),
               MFMA16(A2d[0], __builtin_bit_cast(short8, d0), zero4));
    };

    // ---- main time loop: pure register dataflow, no LDS, no barriers ----
    for (int s = 0;; s++) {
        short8 zf = mkzfrag(z);
        f32x4 y = decode(zf);
        if (lane < 16) out[(size_t)s * B + wbase + c] = y[0];

        if (s == T - 1) break;
        float dt = tt[s + 1] - tt[s];

        f32x4 k = odef(zf);                          // k1 (shares zf with decode)
        f32x4 ksum = k;
        f32x4 ztmp = z + (0.5f * dt) * k;
        k = odef(mkzfrag(ztmp));                     // k2
        ksum += 2.0f * k;
        ztmp = z + (0.5f * dt) * k;
        k = odef(mkzfrag(ztmp));                     // k3
        ksum += 2.0f * k;
        ztmp = z + dt * k;
        k = odef(mkzfrag(ztmp));                     // k4
        z = z + (dt * (1.0f / 6.0f)) * (ksum + k);
    }
}

extern "C" void kernel_launch(void* const* d_in, const int* in_sizes, int n_in,
                              void* d_out, int out_size, void* d_ws, size_t ws_size,
                              hipStream_t stream) {
    const float* x0  = (const float*)d_in[0];
    const float* t   = (const float*)d_in[1];
    const float* We1 = (const float*)d_in[2];
    const float* be1 = (const float*)d_in[3];
    const float* We2 = (const float*)d_in[4];
    const float* be2 = (const float*)d_in[5];
    const float* Wo1 = (const float*)d_in[6];
    const float* bo1 = (const float*)d_in[7];
    const float* Wo2 = (const float*)d_in[8];
    const float* bo2 = (const float*)d_in[9];
    const float* Wd1 = (const float*)d_in[10];
    const float* bd1 = (const float*)d_in[11];
    const float* Wd2 = (const float*)d_in[12];
    const float* bd2 = (const float*)d_in[13];
    float* out = (float*)d_out;

    int B = in_sizes[0] / 2;   // 65536
    int T = in_sizes[1];       // 100

    dim3 block(BLK);
    dim3 grid(B / (NW * MPW)); // 1024 blocks, 4 independent waves each
    hipLaunchKernelGGL(node_kernel, grid, block, 0, stream,
                       x0, t, We1, be1, We2, be2, Wo1, bo1, Wo2, bo2,
                       Wd1, bd1, Wd2, bd2, out, B, T);
}

// Round 11
// 554.471 us; speedup vs baseline: 1.1515x; 1.1515x over previous
//
#include <hip/hip_runtime.h>
#include <hip/hip_bf16.h>

#define HID 50
#define LAT 16
#define NW  4          // waves per block (fully independent, no LDS, no barriers)
#define BLK (NW * 64)
#define MPW 16         // batch elements per wave
#define LOG2E2 2.8853900817779268f   // 2*log2(e), folded into ODE layer-1 weights

typedef __attribute__((ext_vector_type(8))) short short8;   // 8 bf16 = 4 VGPRs
typedef __attribute__((ext_vector_type(4))) float f32x4;
typedef __attribute__((ext_vector_type(4))) unsigned uint4v;

#define MFMA16(a, b, c) __builtin_amdgcn_mfma_f32_16x16x32_bf16(a, b, c, 0, 0, 0)

// pack two fp32 -> dword of 2 bf16 (RNE). Official HIP conversion: on gfx950
// lowers to one v_cvt_pk_bf16_f32. (__hip_bfloat162 is not trivially copyable
// in this ROCm -> use memcpy, not __builtin_bit_cast; compiles to a reg move.)
__device__ __forceinline__ unsigned pkbf(float lo, float hi) {
    __hip_bfloat162 h = __float22bfloat162_rn(float2{lo, hi});
    unsigned r;
    __builtin_memcpy(&r, &h, 4);
    return r;
}

// tanh(x) given s = 2*log2(e)*x (pre-scaled via MFMA weights).
// tanh = 1 - 2/(1+2^s): 2 trans (exp2, rcp) + 2 VALU.  R9's A/B measured
// E_trans ~= 5.4 cy, so this beats magic+Newton (1 trans + 7 VALU).
// exp2/rcp via builtins -> compiler inserts the TRANS-hazard wait states
// (R8's raw asm skipped them -> NaN).  s=80 sat slot -> t=1 exact; s=0 -> 0.
__device__ __forceinline__ float tanh_s(float s) {
    float e = __builtin_amdgcn_exp2f(s);
    float r = __builtin_amdgcn_rcpf(e + 1.0f);
    return __builtin_fmaf(-2.0f, r, 1.0f);
}

// ---- A-frag builders (weights as MFMA A-operand; one-time setup) ----
// Layer-1 (W[Kreal x 50] row-major, transposed use): A-row m holds hid unit
// kappa(ti,m) = 32*(ti>>1) + 8*(m>>2) + 4*(ti&1) + (m&3); this permutation makes
// GEMM1's CD output registers coincide with GEMM2's B-frag slots (no shuffle).
// k-slot (q,j): j<4 -> input row 4q+j; (q==0,j==4) -> bias*scale; kappa==63 ->
// satval at the bias slot (satval already in the activation's input domain).
__device__ __forceinline__ short8 afrag1(const float* __restrict__ W, const float* __restrict__ bias,
                                         int Kreal, int ti, int q, int m,
                                         float scale, float satval) {
    int kap = 32 * (ti >> 1) + 8 * (m >> 2) + 4 * (ti & 1) + (m & 3);
    float e[8];
#pragma unroll
    for (int j = 0; j < 8; j++) {
        float f = 0.0f;
        if (kap < HID) {
            if (j < 4) {
                int row = 4 * q + j;
                if (row < Kreal) f = W[row * HID + kap] * scale;
            } else if (j == 4 && q == 0) f = bias[kap] * scale;
        } else if (kap == 63) {
            if (j == 4 && q == 0) f = satval;
        }
        e[j] = f;
    }
    uint4v d;
#pragma unroll
    for (int p = 0; p < 4; p++) d[p] = pkbf(e[2 * p], e[2 * p + 1]);
    return __builtin_bit_cast(short8, d);
}

// Layer-2 (W2[50 x N2] row-major): A2[m][kap] = W2[kap][m] for kap<50, bias at kap==63.
__device__ __forceinline__ short8 afrag2(const float* __restrict__ W2, const float* __restrict__ b2,
                                         int N2, int chunk, int q, int m) {
    float e[8];
#pragma unroll
    for (int j = 0; j < 8; j++) {
        int kap = 32 * chunk + 8 * q + j;
        float f = 0.0f;
        if (m < N2) {
            if (kap < HID)      f = W2[kap * N2 + m];
            else if (kap == 63) f = b2[m];
        }
        e[j] = f;
    }
    uint4v d;
#pragma unroll
    for (int p = 0; p < 4; p++) d[p] = pkbf(e[2 * p], e[2 * p + 1]);
    return __builtin_bit_cast(short8, d);
}

__global__ void __launch_bounds__(BLK, 4)
node_kernel(const float* __restrict__ x0, const float* __restrict__ tt,
            const float* __restrict__ We1, const float* __restrict__ be1,
            const float* __restrict__ We2, const float* __restrict__ be2,
            const float* __restrict__ Wo1, const float* __restrict__ bo1,
            const float* __restrict__ Wo2, const float* __restrict__ bo2,
            const float* __restrict__ Wd1, const float* __restrict__ bd1,
            const float* __restrict__ Wd2, const float* __restrict__ bd2,
            float* __restrict__ out, int B, int T) {
    const int lane = threadIdx.x & 63;
    const int q    = lane >> 4;          // quad
    const int c    = lane & 15;          // batch col in B/CD frags; row m in A frags
    const int wid  = threadIdx.x >> 6;
    const int wbase = blockIdx.x * (NW * MPW) + wid * MPW;

    const f32x4 zero4 = {0.0f, 0.0f, 0.0f, 0.0f};
    const unsigned biasdw = (q == 0) ? 0x3F80u : 0u;   // bf16(1.0) at k-slot j=4

    // ---- Encoder (transient frags): z^T = We2^T @ relu(We1^T @ x^T) ----
    f32x4 z;
    {
        uint4v bx = {0u, 0u, 0u, 0u};
        if (q == 0) {  // x at k=0,1; bias 1.0 at k=4
            bx[0] = pkbf(x0[2 * (wbase + c)], x0[2 * (wbase + c) + 1]);
            bx[2] = 0x3F80u;
        }
        short8 Bx = __builtin_bit_cast(short8, bx);
        f32x4 h0 = MFMA16(afrag1(We1, be1, 2, 0, q, c, 1.0f, 1.0f), Bx, zero4);
        f32x4 h1 = MFMA16(afrag1(We1, be1, 2, 1, q, c, 1.0f, 1.0f), Bx, zero4);
        f32x4 h2 = MFMA16(afrag1(We1, be1, 2, 2, q, c, 1.0f, 1.0f), Bx, zero4);
        f32x4 h3 = MFMA16(afrag1(We1, be1, 2, 3, q, c, 1.0f, 1.0f), Bx, zero4);
        uint4v d0 = {pkbf(fmaxf(h0[0], 0.f), fmaxf(h0[1], 0.f)), pkbf(fmaxf(h0[2], 0.f), fmaxf(h0[3], 0.f)),
                     pkbf(fmaxf(h1[0], 0.f), fmaxf(h1[1], 0.f)), pkbf(fmaxf(h1[2], 0.f), fmaxf(h1[3], 0.f))};
        uint4v d1 = {pkbf(fmaxf(h2[0], 0.f), fmaxf(h2[1], 0.f)), pkbf(fmaxf(h2[2], 0.f), fmaxf(h2[3], 0.f)),
                     pkbf(fmaxf(h3[0], 0.f), fmaxf(h3[1], 0.f)), pkbf(fmaxf(h3[2], 0.f), fmaxf(h3[3], 0.f))};
        z = MFMA16(afrag2(We2, be2, 16, 1, q, c), __builtin_bit_cast(short8, d1),
            MFMA16(afrag2(We2, be2, 16, 0, q, c), __builtin_bit_cast(short8, d0), zero4));
    }

    // ---- persistent weight A-frags (VGPRs for whole kernel) ----
    // ODE layer-1 pre-scaled by 2*log2(e): MFMA emits the exp2 argument directly.
    short8 A1o[4], A1d[4], A2o[2], A2d[2];
#pragma unroll
    for (int ti = 0; ti < 4; ti++) {
        A1o[ti] = afrag1(Wo1, bo1, LAT, ti, q, c, LOG2E2, 80.0f);  // tanh_s(80)==1.0
        A1d[ti] = afrag1(Wd1, bd1, LAT, ti, q, c, 1.0f, 1.0f);     // relu(1)==1.0
    }
#pragma unroll
    for (int ch = 0; ch < 2; ch++) {
        A2o[ch] = afrag2(Wo2, bo2, LAT, ch, q, c);
        A2d[ch] = afrag2(Wd2, bd2, 1, ch, q, c);
    }

    // z (CD layout: lat 4q+r, batch c) -> GEMM1 B-frag: k(j<4)=lat 4q+j, bias at k=4
    auto mkzfrag = [&](f32x4 zz) -> short8 {
        uint4v d = {pkbf(zz[0], zz[1]), pkbf(zz[2], zz[3]), biasdw, 0u};
        return __builtin_bit_cast(short8, d);
    };

    // ODE func, all in registers: 6 MFMA + 16 tanh_s + 8 packs
    auto odef = [&](short8 zf) -> f32x4 {
        f32x4 h0 = MFMA16(A1o[0], zf, zero4);
        f32x4 h1 = MFMA16(A1o[1], zf, zero4);
        f32x4 h2 = MFMA16(A1o[2], zf, zero4);
        f32x4 h3 = MFMA16(A1o[3], zf, zero4);
        uint4v d0 = {pkbf(tanh_s(h0[0]), tanh_s(h0[1])), pkbf(tanh_s(h0[2]), tanh_s(h0[3])),
                     pkbf(tanh_s(h1[0]), tanh_s(h1[1])), pkbf(tanh_s(h1[2]), tanh_s(h1[3]))};
        uint4v d1 = {pkbf(tanh_s(h2[0]), tanh_s(h2[1])), pkbf(tanh_s(h2[2]), tanh_s(h2[3])),
                     pkbf(tanh_s(h3[0]), tanh_s(h3[1])), pkbf(tanh_s(h3[2]), tanh_s(h3[3]))};
        return MFMA16(A2o[1], __builtin_bit_cast(short8, d1),
               MFMA16(A2o[0], __builtin_bit_cast(short8, d0), zero4));
    };

    // decoder: y[c] lands in reg0 of q==0 lanes
    auto decode = [&](short8 zf) -> f32x4 {
        f32x4 h0 = MFMA16(A1d[0], zf, zero4);
        f32x4 h1 = MFMA16(A1d[1], zf, zero4);
        f32x4 h2 = MFMA16(A1d[2], zf, zero4);
        f32x4 h3 = MFMA16(A1d[3], zf, zero4);
        uint4v d0 = {pkbf(fmaxf(h0[0], 0.f), fmaxf(h0[1], 0.f)), pkbf(fmaxf(h0[2], 0.f), fmaxf(h0[3], 0.f)),
                     pkbf(fmaxf(h1[0], 0.f), fmaxf(h1[1], 0.f)), pkbf(fmaxf(h1[2], 0.f), fmaxf(h1[3], 0.f))};
        uint4v d1 = {pkbf(fmaxf(h2[0], 0.f), fmaxf(h2[1], 0.f)), pkbf(fmaxf(h2[2], 0.f), fmaxf(h2[3], 0.f)),
                     pkbf(fmaxf(h3[0], 0.f), fmaxf(h3[1], 0.f)), pkbf(fmaxf(h3[2], 0.f), fmaxf(h3[3], 0.f))};
        return MFMA16(A2d[1], __builtin_bit_cast(short8, d1),
               MFMA16(A2d[0], __builtin_bit_cast(short8, d0), zero4));
    };

    // ---- main time loop: pure register dataflow, no LDS, no barriers ----
    for (int s = 0;; s++) {
        short8 zf = mkzfrag(z);
        f32x4 y = decode(zf);
        if (lane < 16) out[(size_t)s * B + wbase + c] = y[0];

        if (s == T - 1) break;
        float dt = tt[s + 1] - tt[s];

        f32x4 k = odef(zf);                          // k1 (shares zf with decode)
        f32x4 ksum = k;
        f32x4 ztmp = z + (0.5f * dt) * k;
        k = odef(mkzfrag(ztmp));                     // k2
        ksum += 2.0f * k;
        ztmp = z + (0.5f * dt) * k;
        k = odef(mkzfrag(ztmp));                     // k3
        ksum += 2.0f * k;
        ztmp = z + dt * k;
        k = odef(mkzfrag(ztmp));                     // k4
        z = z + (dt * (1.0f / 6.0f)) * (ksum + k);
    }
}

extern "C" void kernel_launch(void* const* d_in, const int* in_sizes, int n_in,
                              void* d_out, int out_size, void* d_ws, size_t ws_size,
                              hipStream_t stream) {
    const float* x0  = (const float*)d_in[0];
    const float* t   = (const float*)d_in[1];
    const float* We1 = (const float*)d_in[2];
    const float* be1 = (const float*)d_in[3];
    const float* We2 = (const float*)d_in[4];
    const float* be2 = (const float*)d_in[5];
    const float* Wo1 = (const float*)d_in[6];
    const float* bo1 = (const float*)d_in[7];
    const float* Wo2 = (const float*)d_in[8];
    const float* bo2 = (const float*)d_in[9];
    const float* Wd1 = (const float*)d_in[10];
    const float* bd1 = (const float*)d_in[11];
    const float* Wd2 = (const float*)d_in[12];
    const float* bd2 = (const float*)d_in[13];
    float* out = (float*)d_out;

    int B = in_sizes[0] / 2;   // 65536
    int T = in_sizes[1];       // 100

    dim3 block(BLK);
    dim3 grid(B / (NW * MPW)); // 1024 blocks, 4 independent waves each
    hipLaunchKernelGGL(node_kernel, grid, block, 0, stream,
                       x0, t, We1, be1, We2, be2, Wo1, bo1, Wo2, bo2,
                       Wd1, bd1, Wd2, bd2, out, B, T);
}

// Round 12
// 550.686 us; speedup vs baseline: 1.1594x; 1.0069x over previous
//
#include <hip/hip_runtime.h>
#include <hip/hip_bf16.h>

#define HID 50
#define LAT 16
#define NW  4          // waves per block (independent after the one-time dt staging)
#define BLK (NW * 64)
#define MPW 16         // batch elements per wave
#define LOG2E2 2.8853900817779268f   // 2*log2(e), folded into ODE layer-1 weights

typedef __attribute__((ext_vector_type(8))) short short8;   // 8 bf16 = 4 VGPRs
typedef __attribute__((ext_vector_type(4))) float f32x4;
typedef __attribute__((ext_vector_type(4))) unsigned uint4v;

#define MFMA16(a, b, c) __builtin_amdgcn_mfma_f32_16x16x32_bf16(a, b, c, 0, 0, 0)

// pack two fp32 -> dword of 2 bf16 (RNE); lowers to one v_cvt_pk_bf16_f32.
__device__ __forceinline__ unsigned pkbf(float lo, float hi) {
    __hip_bfloat162 h = __float22bfloat162_rn(float2{lo, hi});
    unsigned r;
    __builtin_memcpy(&r, &h, 4);
    return r;
}

// tanh(x) given s = 2*log2(e)*x (pre-scaled via MFMA weights).
// tanh = 1 - 2/(1+2^s): 2 trans + 2 VALU. E_trans ~4 cy (R7/R9/R11 A/Bs) ->
// this is the issue-optimal form. s=80 sat slot -> t=1 exact; s=0 -> 0 exact.
__device__ __forceinline__ float tanh_s(float s) {
    float e = __builtin_amdgcn_exp2f(s);
    float r = __builtin_amdgcn_rcpf(e + 1.0f);
    return __builtin_fmaf(-2.0f, r, 1.0f);
}

// ---- A-frag builders (weights as MFMA A-operand; one-time setup) ----
// Layer-1: A-row m holds hid unit kappa(ti,m)=32*(ti>>1)+8*(m>>2)+4*(ti&1)+(m&3)
// so GEMM1's CD registers coincide with GEMM2's B-frag slots (no shuffle).
// k-slot (q,j): j<4 -> input row 4q+j; (q==0,j==4) -> bias*scale; kappa==63 ->
// satval at the bias slot.
__device__ __forceinline__ short8 afrag1(const float* __restrict__ W, const float* __restrict__ bias,
                                         int Kreal, int ti, int q, int m,
                                         float scale, float satval) {
    int kap = 32 * (ti >> 1) + 8 * (m >> 2) + 4 * (ti & 1) + (m & 3);
    float e[8];
#pragma unroll
    for (int j = 0; j < 8; j++) {
        float f = 0.0f;
        if (kap < HID) {
            if (j < 4) {
                int row = 4 * q + j;
                if (row < Kreal) f = W[row * HID + kap] * scale;
            } else if (j == 4 && q == 0) f = bias[kap] * scale;
        } else if (kap == 63) {
            if (j == 4 && q == 0) f = satval;
        }
        e[j] = f;
    }
    uint4v d;
#pragma unroll
    for (int p = 0; p < 4; p++) d[p] = pkbf(e[2 * p], e[2 * p + 1]);
    return __builtin_bit_cast(short8, d);
}

// Layer-2 (W2[50 x N2] row-major): A2[m][kap] = W2[kap][m] for kap<50, bias at kap==63.
__device__ __forceinline__ short8 afrag2(const float* __restrict__ W2, const float* __restrict__ b2,
                                         int N2, int chunk, int q, int m) {
    float e[8];
#pragma unroll
    for (int j = 0; j < 8; j++) {
        int kap = 32 * chunk + 8 * q + j;
        float f = 0.0f;
        if (m < N2) {
            if (kap < HID)      f = W2[kap * N2 + m];
            else if (kap == 63) f = b2[m];
        }
        e[j] = f;
    }
    uint4v d;
#pragma unroll
    for (int p = 0; p < 4; p++) d[p] = pkbf(e[2 * p], e[2 * p + 1]);
    return __builtin_bit_cast(short8, d);
}

__global__ void __launch_bounds__(BLK, 4)
node_kernel(const float* __restrict__ x0, const float* __restrict__ tt,
            const float* __restrict__ We1, const float* __restrict__ be1,
            const float* __restrict__ We2, const float* __restrict__ be2,
            const float* __restrict__ Wo1, const float* __restrict__ bo1,
            const float* __restrict__ Wo2, const float* __restrict__ bo2,
            const float* __restrict__ Wd1, const float* __restrict__ bd1,
            const float* __restrict__ Wd2, const float* __restrict__ bd2,
            float* __restrict__ out, int B, int T) {
    // dt table in LDS: per-step dt comes from ds_read (lgkmcnt), NOT a VMEM load.
    // This keeps the K-loop free of any vmcnt dependency -> the out[] store is
    // never drained (R11 theory: per-step vmcnt(0) on the dt load serialized
    // every wave on its own HBM store ack).
    __shared__ float sdt[128];
    {
        int idx = threadIdx.x;
        if (idx < T - 1) sdt[idx] = tt[idx + 1] - tt[idx];
    }
    __syncthreads();   // one-time; waves independent afterwards

    const int lane = threadIdx.x & 63;
    const int q    = lane >> 4;          // quad
    const int c    = lane & 15;          // batch col in B/CD frags; row m in A frags
    const int wid  = threadIdx.x >> 6;
    const int wbase = blockIdx.x * (NW * MPW) + wid * MPW;

    const f32x4 zero4 = {0.0f, 0.0f, 0.0f, 0.0f};
    const unsigned biasdw = (q == 0) ? 0x3F80u : 0u;   // bf16(1.0) at k-slot j=4

    // ---- Encoder (transient frags): z^T = We2^T @ relu(We1^T @ x^T) ----
    f32x4 z;
    {
        uint4v bx = {0u, 0u, 0u, 0u};
        if (q == 0) {  // x at k=0,1; bias 1.0 at k=4
            bx[0] = pkbf(x0[2 * (wbase + c)], x0[2 * (wbase + c) + 1]);
            bx[2] = 0x3F80u;
        }
        short8 Bx = __builtin_bit_cast(short8, bx);
        f32x4 h0 = MFMA16(afrag1(We1, be1, 2, 0, q, c, 1.0f, 1.0f), Bx, zero4);
        f32x4 h1 = MFMA16(afrag1(We1, be1, 2, 1, q, c, 1.0f, 1.0f), Bx, zero4);
        f32x4 h2 = MFMA16(afrag1(We1, be1, 2, 2, q, c, 1.0f, 1.0f), Bx, zero4);
        f32x4 h3 = MFMA16(afrag1(We1, be1, 2, 3, q, c, 1.0f, 1.0f), Bx, zero4);
        uint4v d0 = {pkbf(fmaxf(h0[0], 0.f), fmaxf(h0[1], 0.f)), pkbf(fmaxf(h0[2], 0.f), fmaxf(h0[3], 0.f)),
                     pkbf(fmaxf(h1[0], 0.f), fmaxf(h1[1], 0.f)), pkbf(fmaxf(h1[2], 0.f), fmaxf(h1[3], 0.f))};
        uint4v d1 = {pkbf(fmaxf(h2[0], 0.f), fmaxf(h2[1], 0.f)), pkbf(fmaxf(h2[2], 0.f), fmaxf(h2[3], 0.f)),
                     pkbf(fmaxf(h3[0], 0.f), fmaxf(h3[1], 0.f)), pkbf(fmaxf(h3[2], 0.f), fmaxf(h3[3], 0.f))};
        z = MFMA16(afrag2(We2, be2, 16, 1, q, c), __builtin_bit_cast(short8, d1),
            MFMA16(afrag2(We2, be2, 16, 0, q, c), __builtin_bit_cast(short8, d0), zero4));
    }

    // ---- persistent weight A-frags (register file for the whole kernel) ----
    short8 A1o[4], A1d[4], A2o[2], A2d[2];
#pragma unroll
    for (int ti = 0; ti < 4; ti++) {
        A1o[ti] = afrag1(Wo1, bo1, LAT, ti, q, c, LOG2E2, 80.0f);  // tanh_s(80)==1.0
        A1d[ti] = afrag1(Wd1, bd1, LAT, ti, q, c, 1.0f, 1.0f);     // relu(1)==1.0
    }
#pragma unroll
    for (int ch = 0; ch < 2; ch++) {
        A2o[ch] = afrag2(Wo2, bo2, LAT, ch, q, c);
        A2d[ch] = afrag2(Wd2, bd2, 1, ch, q, c);
    }

    // z (CD layout: lat 4q+r, batch c) -> GEMM1 B-frag: k(j<4)=lat 4q+j, bias at k=4
    auto mkzfrag = [&](f32x4 zz) -> short8 {
        uint4v d = {pkbf(zz[0], zz[1]), pkbf(zz[2], zz[3]), biasdw, 0u};
        return __builtin_bit_cast(short8, d);
    };

    // ODE func, all in registers: 6 MFMA + 16 tanh_s + 8 packs
    auto odef = [&](short8 zf) -> f32x4 {
        f32x4 h0 = MFMA16(A1o[0], zf, zero4);
        f32x4 h1 = MFMA16(A1o[1], zf, zero4);
        f32x4 h2 = MFMA16(A1o[2], zf, zero4);
        f32x4 h3 = MFMA16(A1o[3], zf, zero4);
        uint4v d0 = {pkbf(tanh_s(h0[0]), tanh_s(h0[1])), pkbf(tanh_s(h0[2]), tanh_s(h0[3])),
                     pkbf(tanh_s(h1[0]), tanh_s(h1[1])), pkbf(tanh_s(h1[2]), tanh_s(h1[3]))};
        uint4v d1 = {pkbf(tanh_s(h2[0]), tanh_s(h2[1])), pkbf(tanh_s(h2[2]), tanh_s(h2[3])),
                     pkbf(tanh_s(h3[0]), tanh_s(h3[1])), pkbf(tanh_s(h3[2]), tanh_s(h3[3]))};
        return MFMA16(A2o[1], __builtin_bit_cast(short8, d1),
               MFMA16(A2o[0], __builtin_bit_cast(short8, d0), zero4));
    };

    // decoder: y[c] lands in reg0 of q==0 lanes
    auto decode = [&](short8 zf) -> f32x4 {
        f32x4 h0 = MFMA16(A1d[0], zf, zero4);
        f32x4 h1 = MFMA16(A1d[1], zf, zero4);
        f32x4 h2 = MFMA16(A1d[2], zf, zero4);
        f32x4 h3 = MFMA16(A1d[3], zf, zero4);
        uint4v d0 = {pkbf(fmaxf(h0[0], 0.f), fmaxf(h0[1], 0.f)), pkbf(fmaxf(h0[2], 0.f), fmaxf(h0[3], 0.f)),
                     pkbf(fmaxf(h1[0], 0.f), fmaxf(h1[1], 0.f)), pkbf(fmaxf(h1[2], 0.f), fmaxf(h1[3], 0.f))};
        uint4v d1 = {pkbf(fmaxf(h2[0], 0.f), fmaxf(h2[1], 0.f)), pkbf(fmaxf(h2[2], 0.f), fmaxf(h2[3], 0.f)),
                     pkbf(fmaxf(h3[0], 0.f), fmaxf(h3[1], 0.f)), pkbf(fmaxf(h3[2], 0.f), fmaxf(h3[3], 0.f))};
        return MFMA16(A2d[1], __builtin_bit_cast(short8, d1),
               MFMA16(A2d[0], __builtin_bit_cast(short8, d0), zero4));
    };

    // ---- main time loop: register dataflow; only VMEM op is the out store ----
    for (int s = 0;; s++) {
        float dt = sdt[s];                 // ds_read at loop-top; latency hides
                                           // behind decode + k1 (no vmcnt tie)
        short8 zf = mkzfrag(z);
        f32x4 y = decode(zf);
        if (lane < 16) out[(size_t)s * B + wbase + c] = y[0];

        if (s == T - 1) break;

        f32x4 k = odef(zf);                          // k1 (shares zf with decode)
        f32x4 ksum = k;
        f32x4 ztmp = z + (0.5f * dt) * k;
        k = odef(mkzfrag(ztmp));                     // k2
        ksum += 2.0f * k;
        ztmp = z + (0.5f * dt) * k;
        k = odef(mkzfrag(ztmp));                     // k3
        ksum += 2.0f * k;
        ztmp = z + dt * k;
        k = odef(mkzfrag(ztmp));                     // k4
        z = z + (dt * (1.0f / 6.0f)) * (ksum + k);
    }
}

extern "C" void kernel_launch(void* const* d_in, const int* in_sizes, int n_in,
                              void* d_out, int out_size, void* d_ws, size_t ws_size,
                              hipStream_t stream) {
    const float* x0  = (const float*)d_in[0];
    const float* t   = (const float*)d_in[1];
    const float* We1 = (const float*)d_in[2];
    const float* be1 = (const float*)d_in[3];
    const float* We2 = (const float*)d_in[4];
    const float* be2 = (const float*)d_in[5];
    const float* Wo1 = (const float*)d_in[6];
    const float* bo1 = (const float*)d_in[7];
    const float* Wo2 = (const float*)d_in[8];
    const float* bo2 = (const float*)d_in[9];
    const float* Wd1 = (const float*)d_in[10];
    const float* bd1 = (const float*)d_in[11];
    const float* Wd2 = (const float*)d_in[12];
    const float* bd2 = (const float*)d_in[13];
    float* out = (float*)d_out;

    int B = in_sizes[0] / 2;   // 65536
    int T = in_sizes[1];       // 100

    dim3 block(BLK);
    dim3 grid(B / (NW * MPW)); // 1024 blocks, 4 waves each
    hipLaunchKernelGGL(node_kernel, grid, block, 0, stream,
                       x0, t, We1, be1, We2, be2, Wo1, bo1, Wo2, bo2,
                       Wd1, bd1, Wd2, bd2, out, B, T);
}

// Round 13
// 547.149 us; speedup vs baseline: 1.1669x; 1.0065x over previous
//
#include <hip/hip_runtime.h>
#include <hip/hip_bf16.h>

#define HID 50
#define LAT 16
#define NW  4          // waves per block
#define BLK (NW * 64)
#define EPW 32         // batch elements per wave = 2 independent M=16 pipelines
#define LOG2E2 2.8853900817779268f   // 2*log2(e), folded into ODE layer-1 weights

typedef __attribute__((ext_vector_type(8))) short short8;   // 8 bf16 = 4 VGPRs
typedef __attribute__((ext_vector_type(4))) float f32x4;
typedef __attribute__((ext_vector_type(4))) unsigned uint4v;

#define MFMA16(a, b, c) __builtin_amdgcn_mfma_f32_16x16x32_bf16(a, b, c, 0, 0, 0)

// pack two fp32 -> dword of 2 bf16 (RNE); lowers to one v_cvt_pk_bf16_f32.
__device__ __forceinline__ unsigned pkbf(float lo, float hi) {
    __hip_bfloat162 h = __float22bfloat162_rn(float2{lo, hi});
    unsigned r;
    __builtin_memcpy(&r, &h, 4);
    return r;
}

// tanh(x) given s = 2*log2(e)*x (pre-scaled in weights): 1 - 2/(1+2^s).
// 2 trans + 2 VALU, shortest dependent chain (R9 A/B: Newton chain is worse).
__device__ __forceinline__ float tanh_s(float s) {
    float e = __builtin_amdgcn_exp2f(s);
    float r = __builtin_amdgcn_rcpf(e + 1.0f);
    return __builtin_fmaf(-2.0f, r, 1.0f);
}

// ---- A-frag builders (weights as MFMA A-operand; one-time setup) ----
// Layer-1: A-row m holds hid unit kappa(ti,m)=32*(ti>>1)+8*(m>>2)+4*(ti&1)+(m&3)
// so GEMM1's CD registers coincide with GEMM2's B-frag slots (no shuffle).
// k-slot (q,j): j<4 -> input row 4q+j; (q==0,j==4) -> bias*scale; kappa==63 ->
// satval at the bias slot.
__device__ __forceinline__ short8 afrag1(const float* __restrict__ W, const float* __restrict__ bias,
                                         int Kreal, int ti, int q, int m,
                                         float scale, float satval) {
    int kap = 32 * (ti >> 1) + 8 * (m >> 2) + 4 * (ti & 1) + (m & 3);
    float e[8];
#pragma unroll
    for (int j = 0; j < 8; j++) {
        float f = 0.0f;
        if (kap < HID) {
            if (j < 4) {
                int row = 4 * q + j;
                if (row < Kreal) f = W[row * HID + kap] * scale;
            } else if (j == 4 && q == 0) f = bias[kap] * scale;
        } else if (kap == 63) {
            if (j == 4 && q == 0) f = satval;
        }
        e[j] = f;
    }
    uint4v d;
#pragma unroll
    for (int p = 0; p < 4; p++) d[p] = pkbf(e[2 * p], e[2 * p + 1]);
    return __builtin_bit_cast(short8, d);
}

// Layer-2 (W2[50 x N2] row-major): A2[m][kap] = W2[kap][m] for kap<50, bias at kap==63.
__device__ __forceinline__ short8 afrag2(const float* __restrict__ W2, const float* __restrict__ b2,
                                         int N2, int chunk, int q, int m) {
    float e[8];
#pragma unroll
    for (int j = 0; j < 8; j++) {
        int kap = 32 * chunk + 8 * q + j;
        float f = 0.0f;
        if (m < N2) {
            if (kap < HID)      f = W2[kap * N2 + m];
            else if (kap == 63) f = b2[m];
        }
        e[j] = f;
    }
    uint4v d;
#pragma unroll
    for (int p = 0; p < 4; p++) d[p] = pkbf(e[2 * p], e[2 * p + 1]);
    return __builtin_bit_cast(short8, d);
}

// __launch_bounds__(256, 2): min-2-waves/EU -> 256-VGPR cap.  R12's (256,4)
// made the compiler squeeze to 52 VGPRs (8-wave occupancy tier the grid never
// uses), serializing the tanh/MFMA chains through a tiny register window.
__global__ void __launch_bounds__(BLK, 2)
node_kernel(const float* __restrict__ x0, const float* __restrict__ tt,
            const float* __restrict__ We1, const float* __restrict__ be1,
            const float* __restrict__ We2, const float* __restrict__ be2,
            const float* __restrict__ Wo1, const float* __restrict__ bo1,
            const float* __restrict__ Wo2, const float* __restrict__ bo2,
            const float* __restrict__ Wd1, const float* __restrict__ bd1,
            const float* __restrict__ Wd2, const float* __restrict__ bd2,
            float* __restrict__ out, int B, int T) {
    __shared__ float sdt[128];   // dt table (lgkm-side, keeps loop vmcnt-free)
    {
        int idx = threadIdx.x;
        if (idx < T - 1) sdt[idx] = tt[idx + 1] - tt[idx];
    }
    __syncthreads();   // one-time; waves independent afterwards

    const int lane = threadIdx.x & 63;
    const int q    = lane >> 4;          // quad
    const int c    = lane & 15;          // batch col in B/CD frags; row m in A frags
    const int wid  = threadIdx.x >> 6;
    const int wbase = blockIdx.x * (NW * EPW) + wid * EPW;

    const f32x4 zero4 = {0.0f, 0.0f, 0.0f, 0.0f};
    const unsigned biasdw = (q == 0) ? 0x3F80u : 0u;   // bf16(1.0) at k-slot j=4

    // ---- persistent weight A-frags (shared by both pipelines) ----
    short8 A1o[4], A1d[4], A2o[2], A2d[2];
#pragma unroll
    for (int ti = 0; ti < 4; ti++) {
        A1o[ti] = afrag1(Wo1, bo1, LAT, ti, q, c, LOG2E2, 80.0f);  // tanh_s(80)==1.0
        A1d[ti] = afrag1(Wd1, bd1, LAT, ti, q, c, 1.0f, 1.0f);     // relu(1)==1.0
    }
#pragma unroll
    for (int ch = 0; ch < 2; ch++) {
        A2o[ch] = afrag2(Wo2, bo2, LAT, ch, q, c);
        A2d[ch] = afrag2(Wd2, bd2, 1, ch, q, c);
    }

    // ---- Encoder: two M=16 halves through shared We-frags ----
    f32x4 zA, zB;
    {
        short8 AWe1[4], AWe2[2];
#pragma unroll
        for (int ti = 0; ti < 4; ti++) AWe1[ti] = afrag1(We1, be1, 2, ti, q, c, 1.0f, 1.0f);
#pragma unroll
        for (int ch = 0; ch < 2; ch++) AWe2[ch] = afrag2(We2, be2, 16, ch, q, c);

        auto enc = [&](int off) -> f32x4 {
            uint4v bx = {0u, 0u, 0u, 0u};
            if (q == 0) {  // x at k=0,1; bias 1.0 at k=4
                bx[0] = pkbf(x0[2 * (wbase + off + c)], x0[2 * (wbase + off + c) + 1]);
                bx[2] = 0x3F80u;
            }
            short8 Bx = __builtin_bit_cast(short8, bx);
            f32x4 h0 = MFMA16(AWe1[0], Bx, zero4);
            f32x4 h1 = MFMA16(AWe1[1], Bx, zero4);
            f32x4 h2 = MFMA16(AWe1[2], Bx, zero4);
            f32x4 h3 = MFMA16(AWe1[3], Bx, zero4);
            uint4v d0 = {pkbf(fmaxf(h0[0], 0.f), fmaxf(h0[1], 0.f)), pkbf(fmaxf(h0[2], 0.f), fmaxf(h0[3], 0.f)),
                         pkbf(fmaxf(h1[0], 0.f), fmaxf(h1[1], 0.f)), pkbf(fmaxf(h1[2], 0.f), fmaxf(h1[3], 0.f))};
            uint4v d1 = {pkbf(fmaxf(h2[0], 0.f), fmaxf(h2[1], 0.f)), pkbf(fmaxf(h2[2], 0.f), fmaxf(h2[3], 0.f)),
                         pkbf(fmaxf(h3[0], 0.f), fmaxf(h3[1], 0.f)), pkbf(fmaxf(h3[2], 0.f), fmaxf(h3[3], 0.f))};
            return MFMA16(AWe2[1], __builtin_bit_cast(short8, d1),
                   MFMA16(AWe2[0], __builtin_bit_cast(short8, d0), zero4));
        };
        zA = enc(0);
        zB = enc(16);
    }

    // z (CD layout) -> GEMM1 B-frag: k(j<4)=lat 4q+j, bias at k=4
    auto mkzfrag = [&](f32x4 zz) -> short8 {
        uint4v d = {pkbf(zz[0], zz[1]), pkbf(zz[2], zz[3]), biasdw, 0u};
        return __builtin_bit_cast(short8, d);
    };

    // Two interleaved ODE pipelines: 12 MFMA + 32 tanh, statements paired A/B
    // so the in-order wave always has the sibling chain to issue while one
    // chain's MFMA/trans results are in flight.
    auto odef2 = [&](short8 zfA, short8 zfB, f32x4& oA, f32x4& oB) {
        f32x4 a0 = MFMA16(A1o[0], zfA, zero4);
        f32x4 b0 = MFMA16(A1o[0], zfB, zero4);
        f32x4 a1 = MFMA16(A1o[1], zfA, zero4);
        f32x4 b1 = MFMA16(A1o[1], zfB, zero4);
        f32x4 a2 = MFMA16(A1o[2], zfA, zero4);
        f32x4 b2 = MFMA16(A1o[2], zfB, zero4);
        f32x4 a3 = MFMA16(A1o[3], zfA, zero4);
        f32x4 b3 = MFMA16(A1o[3], zfB, zero4);
        uint4v dA0 = {pkbf(tanh_s(a0[0]), tanh_s(a0[1])), pkbf(tanh_s(a0[2]), tanh_s(a0[3])),
                      pkbf(tanh_s(a1[0]), tanh_s(a1[1])), pkbf(tanh_s(a1[2]), tanh_s(a1[3]))};
        uint4v dB0 = {pkbf(tanh_s(b0[0]), tanh_s(b0[1])), pkbf(tanh_s(b0[2]), tanh_s(b0[3])),
                      pkbf(tanh_s(b1[0]), tanh_s(b1[1])), pkbf(tanh_s(b1[2]), tanh_s(b1[3]))};
        uint4v dA1 = {pkbf(tanh_s(a2[0]), tanh_s(a2[1])), pkbf(tanh_s(a2[2]), tanh_s(a2[3])),
                      pkbf(tanh_s(a3[0]), tanh_s(a3[1])), pkbf(tanh_s(a3[2]), tanh_s(a3[3]))};
        uint4v dB1 = {pkbf(tanh_s(b2[0]), tanh_s(b2[1])), pkbf(tanh_s(b2[2]), tanh_s(b2[3])),
                      pkbf(tanh_s(b3[0]), tanh_s(b3[1])), pkbf(tanh_s(b3[2]), tanh_s(b3[3]))};
        f32x4 cA = MFMA16(A2o[0], __builtin_bit_cast(short8, dA0), zero4);
        f32x4 cB = MFMA16(A2o[0], __builtin_bit_cast(short8, dB0), zero4);
        oA = MFMA16(A2o[1], __builtin_bit_cast(short8, dA1), cA);
        oB = MFMA16(A2o[1], __builtin_bit_cast(short8, dB1), cB);
    };

    auto decode2 = [&](short8 zfA, short8 zfB, f32x4& yA, f32x4& yB) {
        f32x4 a0 = MFMA16(A1d[0], zfA, zero4);
        f32x4 b0 = MFMA16(A1d[0], zfB, zero4);
        f32x4 a1 = MFMA16(A1d[1], zfA, zero4);
        f32x4 b1 = MFMA16(A1d[1], zfB, zero4);
        f32x4 a2 = MFMA16(A1d[2], zfA, zero4);
        f32x4 b2 = MFMA16(A1d[2], zfB, zero4);
        f32x4 a3 = MFMA16(A1d[3], zfA, zero4);
        f32x4 b3 = MFMA16(A1d[3], zfB, zero4);
        uint4v dA0 = {pkbf(fmaxf(a0[0], 0.f), fmaxf(a0[1], 0.f)), pkbf(fmaxf(a0[2], 0.f), fmaxf(a0[3], 0.f)),
                      pkbf(fmaxf(a1[0], 0.f), fmaxf(a1[1], 0.f)), pkbf(fmaxf(a1[2], 0.f), fmaxf(a1[3], 0.f))};
        uint4v dB0 = {pkbf(fmaxf(b0[0], 0.f), fmaxf(b0[1], 0.f)), pkbf(fmaxf(b0[2], 0.f), fmaxf(b0[3], 0.f)),
                      pkbf(fmaxf(b1[0], 0.f), fmaxf(b1[1], 0.f)), pkbf(fmaxf(b1[2], 0.f), fmaxf(b1[3], 0.f))};
        uint4v dA1 = {pkbf(fmaxf(a2[0], 0.f), fmaxf(a2[1], 0.f)), pkbf(fmaxf(a2[2], 0.f), fmaxf(a2[3], 0.f)),
                      pkbf(fmaxf(a3[0], 0.f), fmaxf(a3[1], 0.f)), pkbf(fmaxf(a3[2], 0.f), fmaxf(a3[3], 0.f))};
        uint4v dB1 = {pkbf(fmaxf(b2[0], 0.f), fmaxf(b2[1], 0.f)), pkbf(fmaxf(b2[2], 0.f), fmaxf(b2[3], 0.f)),
                      pkbf(fmaxf(b3[0], 0.f), fmaxf(b3[1], 0.f)), pkbf(fmaxf(b3[2], 0.f), fmaxf(b3[3], 0.f))};
        f32x4 cA = MFMA16(A2d[0], __builtin_bit_cast(short8, dA0), zero4);
        f32x4 cB = MFMA16(A2d[0], __builtin_bit_cast(short8, dB0), zero4);
        yA = MFMA16(A2d[1], __builtin_bit_cast(short8, dA1), cA);
        yB = MFMA16(A2d[1], __builtin_bit_cast(short8, dB1), cB);
    };

    // ---- main time loop: two register pipelines, no LDS traffic but sdt ----
    for (int s = 0;; s++) {
        float dt = sdt[s];
        short8 zfA = mkzfrag(zA);
        short8 zfB = mkzfrag(zB);
        f32x4 yA, yB;
        decode2(zfA, zfB, yA, yB);
        if (lane < 16) {
            out[(size_t)s * B + wbase + c]      = yA[0];
            out[(size_t)s * B + wbase + 16 + c] = yB[0];
        }

        if (s == T - 1) break;

        f32x4 kA, kB;
        odef2(zfA, zfB, kA, kB);                       // k1
        f32x4 ksumA = kA, ksumB = kB;
        f32x4 ztA = zA + (0.5f * dt) * kA;
        f32x4 ztB = zB + (0.5f * dt) * kB;
        odef2(mkzfrag(ztA), mkzfrag(ztB), kA, kB);     // k2
        ksumA += 2.0f * kA; ksumB += 2.0f * kB;
        ztA = zA + (0.5f * dt) * kA;
        ztB = zB + (0.5f * dt) * kB;
        odef2(mkzfrag(ztA), mkzfrag(ztB), kA, kB);     // k3
        ksumA += 2.0f * kA; ksumB += 2.0f * kB;
        ztA = zA + dt * kA;
        ztB = zB + dt * kB;
        odef2(mkzfrag(ztA), mkzfrag(ztB), kA, kB);     // k4
        zA = zA + (dt * (1.0f / 6.0f)) * (ksumA + kA);
        zB = zB + (dt * (1.0f / 6.0f)) * (ksumB + kB);
    }
}

extern "C" void kernel_launch(void* const* d_in, const int* in_sizes, int n_in,
                              void* d_out, int out_size, void* d_ws, size_t ws_size,
                              hipStream_t stream) {
    const float* x0  = (const float*)d_in[0];
    const float* t   = (const float*)d_in[1];
    const float* We1 = (const float*)d_in[2];
    const float* be1 = (const float*)d_in[3];
    const float* We2 = (const float*)d_in[4];
    const float* be2 = (const float*)d_in[5];
    const float* Wo1 = (const float*)d_in[6];
    const float* bo1 = (const float*)d_in[7];
    const float* Wo2 = (const float*)d_in[8];
    const float* bo2 = (const float*)d_in[9];
    const float* Wd1 = (const float*)d_in[10];
    const float* bd1 = (const float*)d_in[11];
    const float* Wd2 = (const float*)d_in[12];
    const float* bd2 = (const float*)d_in[13];
    float* out = (float*)d_out;

    int B = in_sizes[0] / 2;   // 65536
    int T = in_sizes[1];       // 100

    dim3 block(BLK);
    dim3 grid(B / (NW * EPW)); // 512 blocks, 4 waves x 32 elements each
    hipLaunchKernelGGL(node_kernel, grid, block, 0, stream,
                       x0, t, We1, be1, We2, be2, Wo1, bo1, Wo2, bo2,
                       Wd1, bd1, Wd2, bd2, out, B, T);
}

// Round 14
// 539.131 us; speedup vs baseline: 1.1842x; 1.0149x over previous
//
#include <hip/hip_runtime.h>
#include <hip/hip_bf16.h>

#define HID 50
#define LAT 16
#define NW  4          // waves per block (independent after one-time dt staging)
#define BLK (NW * 64)
#define MPW 16         // batch elements per wave (one MFMA M-tile)
#define LOG2E2 2.8853900817779268f   // 2*log2(e), folded into ODE layer-1 weights

typedef __attribute__((ext_vector_type(8))) short short8;   // 8 bf16 = 4 VGPRs
typedef __attribute__((ext_vector_type(4))) float f32x4;
typedef __attribute__((ext_vector_type(4))) unsigned uint4v;

#define MFMA16(a, b, c) __builtin_amdgcn_mfma_f32_16x16x32_bf16(a, b, c, 0, 0, 0)

// pack two fp32 -> dword of 2 bf16 (RNE); lowers to one v_cvt_pk_bf16_f32.
__device__ __forceinline__ unsigned pkbf(float lo, float hi) {
    __hip_bfloat162 h = __float22bfloat162_rn(float2{lo, hi});
    unsigned r;
    __builtin_memcpy(&r, &h, 4);
    return r;
}

// ---- A-frag builders (weights as MFMA A-operand; one-time setup) ----
// Layer-1: A-row m holds hid unit kappa(ti,m)=32*(ti>>1)+8*(m>>2)+4*(ti&1)+(m&3)
// so GEMM1's CD registers coincide with GEMM2's B-frag slots (no shuffle).
// k-slot (q,j): j<4 -> input row 4q+j; (q==0,j==4) -> bias*scale; kappa==63 ->
// satval at the bias slot.
__device__ __forceinline__ short8 afrag1(const float* __restrict__ W, const float* __restrict__ bias,
                                         int Kreal, int ti, int q, int m,
                                         float scale, float satval) {
    int kap = 32 * (ti >> 1) + 8 * (m >> 2) + 4 * (ti & 1) + (m & 3);
    float e[8];
#pragma unroll
    for (int j = 0; j < 8; j++) {
        float f = 0.0f;
        if (kap < HID) {
            if (j < 4) {
                int row = 4 * q + j;
                if (row < Kreal) f = W[row * HID + kap] * scale;
            } else if (j == 4 && q == 0) f = bias[kap] * scale;
        } else if (kap == 63) {
            if (j == 4 && q == 0) f = satval;
        }
        e[j] = f;
    }
    uint4v d;
#pragma unroll
    for (int p = 0; p < 4; p++) d[p] = pkbf(e[2 * p], e[2 * p + 1]);
    return __builtin_bit_cast(short8, d);
}

// Layer-2 (W2[50 x N2] row-major): A2[m][kap] = W2[kap][m] for kap<50, bias at kap==63.
__device__ __forceinline__ short8 afrag2(const float* __restrict__ W2, const float* __restrict__ b2,
                                         int N2, int chunk, int q, int m) {
    float e[8];
#pragma unroll
    for (int j = 0; j < 8; j++) {
        int kap = 32 * chunk + 8 * q + j;
        float f = 0.0f;
        if (m < N2) {
            if (kap < HID)      f = W2[kap * N2 + m];
            else if (kap == 63) f = b2[m];
        }
        e[j] = f;
    }
    uint4v d;
#pragma unroll
    for (int p = 0; p < 4; p++) d[p] = pkbf(e[2 * p], e[2 * p + 1]);
    return __builtin_bit_cast(short8, d);
}

__global__ void __launch_bounds__(BLK, 4)
node_kernel(const float* __restrict__ x0, const float* __restrict__ tt,
            const float* __restrict__ We1, const float* __restrict__ be1,
            const float* __restrict__ We2, const float* __restrict__ be2,
            const float* __restrict__ Wo1, const float* __restrict__ bo1,
            const float* __restrict__ Wo2, const float* __restrict__ bo2,
            const float* __restrict__ Wd1, const float* __restrict__ bd1,
            const float* __restrict__ Wd2, const float* __restrict__ bd2,
            float* __restrict__ out, int B, int T) {
    __shared__ float sdt[128];   // dt table (lgkm-side; loop stays vmcnt-free)
    {
        int idx = threadIdx.x;
        if (idx < T - 1) sdt[idx] = tt[idx + 1] - tt[idx];
    }
    __syncthreads();   // one-time; waves independent afterwards

    const int lane = threadIdx.x & 63;
    const int q    = lane >> 4;          // quad
    const int c    = lane & 15;          // batch col in B/CD frags; row m in A frags
    const int wid  = threadIdx.x >> 6;
    const int wbase = blockIdx.x * (NW * MPW) + wid * MPW;

    const f32x4 zero4 = {0.0f, 0.0f, 0.0f, 0.0f};
    const unsigned biasdw = (q == 0) ? 0x3F80u : 0u;   // bf16(1.0) at k-slot j=4

    // ---- Encoder (transient frags): z^T = We2^T @ relu(We1^T @ x^T) ----
    f32x4 z;
    {
        uint4v bx = {0u, 0u, 0u, 0u};
        if (q == 0) {  // x at k=0,1; bias 1.0 at k=4
            bx[0] = pkbf(x0[2 * (wbase + c)], x0[2 * (wbase + c) + 1]);
            bx[2] = 0x3F80u;
        }
        short8 Bx = __builtin_bit_cast(short8, bx);
        f32x4 h0 = MFMA16(afrag1(We1, be1, 2, 0, q, c, 1.0f, 1.0f), Bx, zero4);
        f32x4 h1 = MFMA16(afrag1(We1, be1, 2, 1, q, c, 1.0f, 1.0f), Bx, zero4);
        f32x4 h2 = MFMA16(afrag1(We1, be1, 2, 2, q, c, 1.0f, 1.0f), Bx, zero4);
        f32x4 h3 = MFMA16(afrag1(We1, be1, 2, 3, q, c, 1.0f, 1.0f), Bx, zero4);
        uint4v d0 = {pkbf(fmaxf(h0[0], 0.f), fmaxf(h0[1], 0.f)), pkbf(fmaxf(h0[2], 0.f), fmaxf(h0[3], 0.f)),
                     pkbf(fmaxf(h1[0], 0.f), fmaxf(h1[1], 0.f)), pkbf(fmaxf(h1[2], 0.f), fmaxf(h1[3], 0.f))};
        uint4v d1 = {pkbf(fmaxf(h2[0], 0.f), fmaxf(h2[1], 0.f)), pkbf(fmaxf(h2[2], 0.f), fmaxf(h2[3], 0.f)),
                     pkbf(fmaxf(h3[0], 0.f), fmaxf(h3[1], 0.f)), pkbf(fmaxf(h3[2], 0.f), fmaxf(h3[3], 0.f))};
        z = MFMA16(afrag2(We2, be2, 16, 1, q, c), __builtin_bit_cast(short8, d1),
            MFMA16(afrag2(We2, be2, 16, 0, q, c), __builtin_bit_cast(short8, d0), zero4));
    }

    // ---- persistent weight A-frags (register file for the whole kernel) ----
    short8 A1o[4], A1d[4], A2o[2], A2d[2];
#pragma unroll
    for (int ti = 0; ti < 4; ti++) {
        A1o[ti] = afrag1(Wo1, bo1, LAT, ti, q, c, LOG2E2, 80.0f);  // tanh(s=80)==1.0
        A1d[ti] = afrag1(Wd1, bd1, LAT, ti, q, c, 1.0f, 1.0f);     // relu(1)==1.0
    }
#pragma unroll
    for (int ch = 0; ch < 2; ch++) {
        A2o[ch] = afrag2(Wo2, bo2, LAT, ch, q, c);
        A2d[ch] = afrag2(Wd2, bd2, 1, ch, q, c);
    }

    // z (CD layout: lat 4q+r, batch c) -> GEMM1 B-frag: k(j<4)=lat 4q+j, bias at k=4
    auto mkzfrag = [&](f32x4 zz) -> short8 {
        uint4v d = {pkbf(zz[0], zz[1]), pkbf(zz[2], zz[3]), biasdw, 0u};
        return __builtin_bit_cast(short8, d);
    };

    // ODE func with STAGE-SEPARATED tanh: all 16 exp2, then all adds, then all
    // rcps, then all fmas.  sched_barrier(0) fences stop the pressure-min
    // scheduler from re-serializing per-value chains (R13: it emitted 64-VGPR
    // code with each tanh's 4 dependent ops back-to-back -> ~13 cy exposed
    // latency per tanh = the ~60% issue-idle gap).  tanh = 1 - 2/(1+2^s),
    // s pre-scaled by 2*log2(e) in A1o; s=80 sat slot -> 1.0 exact.
    auto odef = [&](short8 zf) -> f32x4 {
        f32x4 h[4];
        h[0] = MFMA16(A1o[0], zf, zero4);
        h[1] = MFMA16(A1o[1], zf, zero4);
        h[2] = MFMA16(A1o[2], zf, zero4);
        h[3] = MFMA16(A1o[3], zf, zero4);
        float e[16], y[16], r[16], t[16];
#pragma unroll
        for (int i = 0; i < 16; i++) e[i] = __builtin_amdgcn_exp2f(h[i >> 2][i & 3]);
        __builtin_amdgcn_sched_barrier(0);
#pragma unroll
        for (int i = 0; i < 16; i++) y[i] = e[i] + 1.0f;
        __builtin_amdgcn_sched_barrier(0);
#pragma unroll
        for (int i = 0; i < 16; i++) r[i] = __builtin_amdgcn_rcpf(y[i]);
        __builtin_amdgcn_sched_barrier(0);
#pragma unroll
        for (int i = 0; i < 16; i++) t[i] = __builtin_fmaf(-2.0f, r[i], 1.0f);
        uint4v d0 = {pkbf(t[0], t[1]), pkbf(t[2], t[3]), pkbf(t[4], t[5]), pkbf(t[6], t[7])};
        uint4v d1 = {pkbf(t[8], t[9]), pkbf(t[10], t[11]), pkbf(t[12], t[13]), pkbf(t[14], t[15])};
        return MFMA16(A2o[1], __builtin_bit_cast(short8, d1),
               MFMA16(A2o[0], __builtin_bit_cast(short8, d0), zero4));
    };

    // decoder (fmax is full-rate; no staging needed): y[c] in reg0 of q==0 lanes
    auto decode = [&](short8 zf) -> f32x4 {
        f32x4 h0 = MFMA16(A1d[0], zf, zero4);
        f32x4 h1 = MFMA16(A1d[1], zf, zero4);
        f32x4 h2 = MFMA16(A1d[2], zf, zero4);
        f32x4 h3 = MFMA16(A1d[3], zf, zero4);
        uint4v d0 = {pkbf(fmaxf(h0[0], 0.f), fmaxf(h0[1], 0.f)), pkbf(fmaxf(h0[2], 0.f), fmaxf(h0[3], 0.f)),
                     pkbf(fmaxf(h1[0], 0.f), fmaxf(h1[1], 0.f)), pkbf(fmaxf(h1[2], 0.f), fmaxf(h1[3], 0.f))};
        uint4v d1 = {pkbf(fmaxf(h2[0], 0.f), fmaxf(h2[1], 0.f)), pkbf(fmaxf(h2[2], 0.f), fmaxf(h2[3], 0.f)),
                     pkbf(fmaxf(h3[0], 0.f), fmaxf(h3[1], 0.f)), pkbf(fmaxf(h3[2], 0.f), fmaxf(h3[3], 0.f))};
        return MFMA16(A2d[1], __builtin_bit_cast(short8, d1),
               MFMA16(A2d[0], __builtin_bit_cast(short8, d0), zero4));
    };

    // ---- main time loop: register dataflow; only VMEM op is the out store ----
    for (int s = 0;; s++) {
        float dt = sdt[s];
        short8 zf = mkzfrag(z);
        f32x4 y = decode(zf);
        if (lane < 16) out[(size_t)s * B + wbase + c] = y[0];

        if (s == T - 1) break;

        f32x4 k = odef(zf);                          // k1 (shares zf with decode)
        f32x4 ksum = k;
        f32x4 ztmp = z + (0.5f * dt) * k;
        k = odef(mkzfrag(ztmp));                     // k2
        ksum += 2.0f * k;
        ztmp = z + (0.5f * dt) * k;
        k = odef(mkzfrag(ztmp));                     // k3
        ksum += 2.0f * k;
        ztmp = z + dt * k;
        k = odef(mkzfrag(ztmp));                     // k4
        z = z + (dt * (1.0f / 6.0f)) * (ksum + k);
    }
}

extern "C" void kernel_launch(void* const* d_in, const int* in_sizes, int n_in,
                              void* d_out, int out_size, void* d_ws, size_t ws_size,
                              hipStream_t stream) {
    const float* x0  = (const float*)d_in[0];
    const float* t   = (const float*)d_in[1];
    const float* We1 = (const float*)d_in[2];
    const float* be1 = (const float*)d_in[3];
    const float* We2 = (const float*)d_in[4];
    const float* be2 = (const float*)d_in[5];
    const float* Wo1 = (const float*)d_in[6];
    const float* bo1 = (const float*)d_in[7];
    const float* Wo2 = (const float*)d_in[8];
    const float* bo2 = (const float*)d_in[9];
    const float* Wd1 = (const float*)d_in[10];
    const float* bd1 = (const float*)d_in[11];
    const float* Wd2 = (const float*)d_in[12];
    const float* bd2 = (const float*)d_in[13];
    float* out = (float*)d_out;

    int B = in_sizes[0] / 2;   // 65536
    int T = in_sizes[1];       // 100

    dim3 block(BLK);
    dim3 grid(B / (NW * MPW)); // 1024 blocks, 4 waves each
    hipLaunchKernelGGL(node_kernel, grid, block, 0, stream,
                       x0, t, We1, be1, We2, be2, Wo1, bo1, Wo2, bo2,
                       Wd1, bd1, Wd2, bd2, out, B, T);
}

// Round 15
// 504.692 us; speedup vs baseline: 1.2650x; 1.0682x over previous
//
#include <hip/hip_runtime.h>
#include <hip/hip_bf16.h>

#define HID 50
#define LAT 16
#define NW  4          // waves per block (independent after one-time dt staging)
#define BLK (NW * 64)
#define MPW 16         // batch elements per wave (one MFMA M-tile)
#define LOG2E2 2.8853900817779268f   // 2*log2(e), folded into ODE layer-1 weights

typedef __attribute__((ext_vector_type(8))) short short8;   // 8 bf16 = 4 VGPRs
typedef __attribute__((ext_vector_type(4))) float f32x4;
typedef __attribute__((ext_vector_type(4))) unsigned uint4v;

#define MFMA16(a, b, c) __builtin_amdgcn_mfma_f32_16x16x32_bf16(a, b, c, 0, 0, 0)

// pack two fp32 -> dword of 2 bf16 (RNE); lowers to one v_cvt_pk_bf16_f32.
__device__ __forceinline__ unsigned pkbf(float lo, float hi) {
    __hip_bfloat162 h = __float22bfloat162_rn(float2{lo, hi});
    unsigned r;
    __builtin_memcpy(&r, &h, 4);
    return r;
}

// kappa-label -> hidden-unit map (R15 repack).  Tiles 0-2 hold real units
// 0..47; tile 3 holds units 48,49 at m=0,1 (q=0), the bias/sat slot at
// kappa==38 (m=2, q=0), everything else dead.  This lets odef/decode evaluate
// the activation on 14 lane-values instead of 16 (-12.5% trans ops) and turns
// the sat slot into the constant biasdw dword (no tanh(80) eval at all).
__device__ __forceinline__ int unitmap(int k, bool& dead, bool& sat) {
    dead = false; sat = false;
    int u = k;
    if (k == 36)                          u = 48;
    else if (k == 37)                     u = 49;
    else if (k == 38)                     sat = true;
    else if (k == 39)                     dead = true;
    else if (k >= 44 && k < 48)           dead = true;
    else if ((k >= 48 && k < 52) || (k >= 56 && k < 60)) u = k - 12;
    else if (k >= 52 && k < 56)           dead = true;
    else if (k >= 60)                     dead = true;
    return u;   // k<36 (not 36-39) and 40-43: identity
}

// ---- A-frag builders (weights as MFMA A-operand; one-time setup) ----
// Layer-1: A-row m of tile ti holds unit unitmap(kappa(ti,m)),
// kappa(ti,m)=32*(ti>>1)+8*(m>>2)+4*(ti&1)+(m&3) -- CD regs land exactly on
// GEMM2 B-frag slots.  k-slot (q,j): j<4 -> input row 4q+j; (q==0,j==4) ->
// bias*scale.  sat/dead columns are all-zero (bias enters via GEMM2 B const).
__device__ __forceinline__ short8 afrag1(const float* __restrict__ W, const float* __restrict__ bias,
                                         int Kreal, int ti, int q, int m, float scale) {
    int kap = 32 * (ti >> 1) + 8 * (m >> 2) + 4 * (ti & 1) + (m & 3);
    bool dead, sat;
    int u = unitmap(kap, dead, sat);
    float e[8];
#pragma unroll
    for (int j = 0; j < 8; j++) {
        float f = 0.0f;
        if (!dead && !sat) {
            if (j < 4) {
                int row = 4 * q + j;
                if (row < Kreal) f = W[row * HID + u] * scale;
            } else if (j == 4 && q == 0) f = bias[u] * scale;
        }
        e[j] = f;
    }
    uint4v d;
#pragma unroll
    for (int p = 0; p < 4; p++) d[p] = pkbf(e[2 * p], e[2 * p + 1]);
    return __builtin_bit_cast(short8, d);
}

// Layer-2: A2[m][kap] = W2[unit(kap)][m]; kappa==38 (sat slot) -> bias row b2[m].
__device__ __forceinline__ short8 afrag2(const float* __restrict__ W2, const float* __restrict__ b2,
                                         int N2, int chunk, int q, int m) {
    float e[8];
#pragma unroll
    for (int j = 0; j < 8; j++) {
        int kap = 32 * chunk + 8 * q + j;
        bool dead, sat;
        int u = unitmap(kap, dead, sat);
        float f = 0.0f;
        if (m < N2) {
            if (sat)       f = b2[m];
            else if (!dead) f = W2[u * N2 + m];
        }
        e[j] = f;
    }
    uint4v d;
#pragma unroll
    for (int p = 0; p < 4; p++) d[p] = pkbf(e[2 * p], e[2 * p + 1]);
    return __builtin_bit_cast(short8, d);
}

__global__ void __launch_bounds__(BLK, 4)
node_kernel(const float* __restrict__ x0, const float* __restrict__ tt,
            const float* __restrict__ We1, const float* __restrict__ be1,
            const float* __restrict__ We2, const float* __restrict__ be2,
            const float* __restrict__ Wo1, const float* __restrict__ bo1,
            const float* __restrict__ Wo2, const float* __restrict__ bo2,
            const float* __restrict__ Wd1, const float* __restrict__ bd1,
            const float* __restrict__ Wd2, const float* __restrict__ bd2,
            float* __restrict__ out, int B, int T) {
    __shared__ float sdt[128];   // dt table (lgkm-side; loop stays vmcnt-free)
    {
        int idx = threadIdx.x;
        if (idx < T - 1) sdt[idx] = tt[idx + 1] - tt[idx];
    }
    __syncthreads();   // one-time; waves independent afterwards

    const int lane = threadIdx.x & 63;
    const int q    = lane >> 4;          // quad
    const int c    = lane & 15;          // batch col in B/CD frags; row m in A frags
    const int wid  = threadIdx.x >> 6;
    const int wbase = blockIdx.x * (NW * MPW) + wid * MPW;

    const f32x4 zero4 = {0.0f, 0.0f, 0.0f, 0.0f};
    // bf16(1.0) in the low half for q==0 lanes: serves BOTH the z-frag bias
    // slot (k=4) and the chunk-1 j=6 sat slot (kappa 38).
    const unsigned biasdw = (q == 0) ? 0x3F80u : 0u;

    // ---- persistent weight A-frags (register file for the whole kernel) ----
    short8 A1o[4], A1d[4], A2o[2], A2d[2];
#pragma unroll
    for (int ti = 0; ti < 4; ti++) {
        A1o[ti] = afrag1(Wo1, bo1, LAT, ti, q, c, LOG2E2);
        A1d[ti] = afrag1(Wd1, bd1, LAT, ti, q, c, 1.0f);
    }
#pragma unroll
    for (int ch = 0; ch < 2; ch++) {
        A2o[ch] = afrag2(Wo2, bo2, LAT, ch, q, c);
        A2d[ch] = afrag2(Wd2, bd2, 1, ch, q, c);
    }

    // ---- Encoder (transient frags), repacked layout, relu on 14 values ----
    f32x4 z;
    {
        uint4v bx = {0u, 0u, 0u, 0u};
        if (q == 0) {  // x at k=0,1; bias 1.0 at k=4
            bx[0] = pkbf(x0[2 * (wbase + c)], x0[2 * (wbase + c) + 1]);
            bx[2] = 0x3F80u;
        }
        short8 Bx = __builtin_bit_cast(short8, bx);
        f32x4 h0 = MFMA16(afrag1(We1, be1, 2, 0, q, c, 1.0f), Bx, zero4);
        f32x4 h1 = MFMA16(afrag1(We1, be1, 2, 1, q, c, 1.0f), Bx, zero4);
        f32x4 h2 = MFMA16(afrag1(We1, be1, 2, 2, q, c, 1.0f), Bx, zero4);
        f32x4 h3 = MFMA16(afrag1(We1, be1, 2, 3, q, c, 1.0f), Bx, zero4);
        uint4v d0 = {pkbf(fmaxf(h0[0], 0.f), fmaxf(h0[1], 0.f)), pkbf(fmaxf(h0[2], 0.f), fmaxf(h0[3], 0.f)),
                     pkbf(fmaxf(h1[0], 0.f), fmaxf(h1[1], 0.f)), pkbf(fmaxf(h1[2], 0.f), fmaxf(h1[3], 0.f))};
        uint4v d1 = {pkbf(fmaxf(h2[0], 0.f), fmaxf(h2[1], 0.f)), pkbf(fmaxf(h2[2], 0.f), fmaxf(h2[3], 0.f)),
                     pkbf(fmaxf(h3[0], 0.f), fmaxf(h3[1], 0.f)), biasdw};
        z = MFMA16(afrag2(We2, be2, 16, 1, q, c), __builtin_bit_cast(short8, d1),
            MFMA16(afrag2(We2, be2, 16, 0, q, c), __builtin_bit_cast(short8, d0), zero4));
    }

    // z (CD layout: lat 4q+r, batch c) -> GEMM1 B-frag: k(j<4)=lat 4q+j, bias at k=4
    auto mkzfrag = [&](f32x4 zz) -> short8 {
        uint4v d = {pkbf(zz[0], zz[1]), pkbf(zz[2], zz[3]), biasdw, 0u};
        return __builtin_bit_cast(short8, d);
    };

    // ODE func: 6 MFMA + 14 staged tanh + 7 packs + 1 const dword.
    // tanh = 1 - 2/(1+2^s), s pre-scaled by 2*log2(e) in A1o.
    auto odef = [&](short8 zf) -> f32x4 {
        f32x4 h0 = MFMA16(A1o[0], zf, zero4);
        f32x4 h1 = MFMA16(A1o[1], zf, zero4);
        f32x4 h2 = MFMA16(A1o[2], zf, zero4);
        f32x4 h3 = MFMA16(A1o[3], zf, zero4);
        float hv[14] = {h0[0], h0[1], h0[2], h0[3], h1[0], h1[1], h1[2], h1[3],
                        h2[0], h2[1], h2[2], h2[3], h3[0], h3[1]};
        float e[14], y[14], r[14], t[14];
#pragma unroll
        for (int i = 0; i < 14; i++) e[i] = __builtin_amdgcn_exp2f(hv[i]);
        __builtin_amdgcn_sched_barrier(0);
#pragma unroll
        for (int i = 0; i < 14; i++) y[i] = e[i] + 1.0f;
        __builtin_amdgcn_sched_barrier(0);
#pragma unroll
        for (int i = 0; i < 14; i++) r[i] = __builtin_amdgcn_rcpf(y[i]);
        __builtin_amdgcn_sched_barrier(0);
#pragma unroll
        for (int i = 0; i < 14; i++) t[i] = __builtin_fmaf(-2.0f, r[i], 1.0f);
        uint4v d0 = {pkbf(t[0], t[1]), pkbf(t[2], t[3]), pkbf(t[4], t[5]), pkbf(t[6], t[7])};
        uint4v d1 = {pkbf(t[8], t[9]), pkbf(t[10], t[11]), pkbf(t[12], t[13]), biasdw};
        return MFMA16(A2o[1], __builtin_bit_cast(short8, d1),
               MFMA16(A2o[0], __builtin_bit_cast(short8, d0), zero4));
    };

    // decoder: relu on 14 values; y[c] lands in reg0 of q==0 lanes
    auto decode = [&](short8 zf) -> f32x4 {
        f32x4 h0 = MFMA16(A1d[0], zf, zero4);
        f32x4 h1 = MFMA16(A1d[1], zf, zero4);
        f32x4 h2 = MFMA16(A1d[2], zf, zero4);
        f32x4 h3 = MFMA16(A1d[3], zf, zero4);
        uint4v d0 = {pkbf(fmaxf(h0[0], 0.f), fmaxf(h0[1], 0.f)), pkbf(fmaxf(h0[2], 0.f), fmaxf(h0[3], 0.f)),
                     pkbf(fmaxf(h1[0], 0.f), fmaxf(h1[1], 0.f)), pkbf(fmaxf(h1[2], 0.f), fmaxf(h1[3], 0.f))};
        uint4v d1 = {pkbf(fmaxf(h2[0], 0.f), fmaxf(h2[1], 0.f)), pkbf(fmaxf(h2[2], 0.f), fmaxf(h2[3], 0.f)),
                     pkbf(fmaxf(h3[0], 0.f), fmaxf(h3[1], 0.f)), biasdw};
        return MFMA16(A2d[1], __builtin_bit_cast(short8, d1),
               MFMA16(A2d[0], __builtin_bit_cast(short8, d0), zero4));
    };

    // ---- main time loop: register dataflow; only VMEM op is the out store ----
    for (int s = 0;; s++) {
        float dt = sdt[s];
        short8 zf = mkzfrag(z);
        f32x4 y = decode(zf);
        if (lane < 16) out[(size_t)s * B + wbase + c] = y[0];

        if (s == T - 1) break;

        f32x4 k = odef(zf);                          // k1 (shares zf with decode)
        f32x4 ksum = k;
        f32x4 ztmp = z + (0.5f * dt) * k;
        k = odef(mkzfrag(ztmp));                     // k2
        ksum += 2.0f * k;
        ztmp = z + (0.5f * dt) * k;
        k = odef(mkzfrag(ztmp));                     // k3
        ksum += 2.0f * k;
        ztmp = z + dt * k;
        k = odef(mkzfrag(ztmp));                     // k4
        z = z + (dt * (1.0f / 6.0f)) * (ksum + k);
    }
}

extern "C" void kernel_launch(void* const* d_in, const int* in_sizes, int n_in,
                              void* d_out, int out_size, void* d_ws, size_t ws_size,
                              hipStream_t stream) {
    const float* x0  = (const float*)d_in[0];
    const float* t   = (const float*)d_in[1];
    const float* We1 = (const float*)d_in[2];
    const float* be1 = (const float*)d_in[3];
    const float* We2 = (const float*)d_in[4];
    const float* be2 = (const float*)d_in[5];
    const float* Wo1 = (const float*)d_in[6];
    const float* bo1 = (const float*)d_in[7];
    const float* Wo2 = (const float*)d_in[8];
    const float* bo2 = (const float*)d_in[9];
    const float* Wd1 = (const float*)d_in[10];
    const float* bd1 = (const float*)d_in[11];
    const float* Wd2 = (const float*)d_in[12];
    const float* bd2 = (const float*)d_in[13];
    float* out = (float*)d_out;

    int B = in_sizes[0] / 2;   // 65536
    int T = in_sizes[1];       // 100

    dim3 block(BLK);
    dim3 grid(B / (NW * MPW)); // 1024 blocks, 4 waves each
    hipLaunchKernelGGL(node_kernel, grid, block, 0, stream,
                       x0, t, We1, be1, We2, be2, Wo1, bo1, Wo2, bo2,
                       Wd1, bd1, Wd2, bd2, out, B, T);
}